// Round 17
// baseline (292.421 us; speedup 1.0000x reference)
//
#include <hip/hip_runtime.h>
#include <hip/hip_bf16.h>
#include <cstdint>
#include <cstddef>

typedef __attribute__((ext_vector_type(8))) short short8;
typedef __attribute__((ext_vector_type(4))) float f32x4;

__device__ __forceinline__ float b2f(ushort u) {
  union { float f; uint32_t i; } x; x.i = ((uint32_t)u) << 16; return x.f;
}
__device__ __forceinline__ ushort f2b(float f) {
  uint32_t i = __builtin_bit_cast(uint32_t, f);
  i += 0x7fffu + ((i >> 16) & 1u);   // RNE
  return (ushort)(i >> 16);
}
__device__ __forceinline__ f32x4 mfma16(short8 a, short8 b, f32x4 c) {
  asm("v_mfma_f32_16x16x32_bf16 %0, %1, %2, %0" : "+v"(c) : "v"(a), "v"(b));
  return c;
}
__device__ __forceinline__ void gload_lds16(const void* g, void* l) {
  auto gp = reinterpret_cast<const __attribute__((address_space(1))) uint32_t*>(
      reinterpret_cast<uintptr_t>(g));
  auto lp = reinterpret_cast<__attribute__((address_space(3))) uint32_t*>(
      reinterpret_cast<uintptr_t>(l));
  __builtin_amdgcn_global_load_lds(gp, lp, 16, 0, 0);
}

// ---------------- conversion kernels ----------------
__global__ __launch_bounds__(256) void k_cvtx(const float* __restrict__ x, ushort* __restrict__ o) {
  size_t i = (size_t)blockIdx.x * 256 + threadIdx.x;           // one per 8 elems
  const float4* xp = (const float4*)x;
  float4 a = xp[i * 2], b = xp[i * 2 + 1];
  union { short8 v; ushort u[8]; } r;
  r.u[0] = f2b(a.x); r.u[1] = f2b(a.y); r.u[2] = f2b(a.z); r.u[3] = f2b(a.w);
  r.u[4] = f2b(b.x); r.u[5] = f2b(b.y); r.u[6] = f2b(b.z); r.u[7] = f2b(b.w);
  *(short8*)&o[i * 8] = r.v;
}

// W[R][C] -> Wt[C][R] (bf16)
__global__ __launch_bounds__(256) void k_cvtT(const float* __restrict__ W, ushort* __restrict__ Wt,
                                              int R, int C) {
  int r = blockIdx.x;
  for (int c = threadIdx.x; c < C; c += 256)
    Wt[(size_t)c * R + r] = f2b(W[(size_t)r * C + c]);
}

// ---------------- CPB (continuous position bias) ----------------
__device__ __forceinline__ float cpb_coord(int i) {
  float v = (float)(i - 11) * (8.0f / 11.0f);
  float l = log2f(fabsf(v) + 1.0f) * (1.0f / 3.0f);
  return v < 0.0f ? -l : l;
}

__global__ void k_cpb1(const float* __restrict__ w1, const float* __restrict__ b1,
                       const float* __restrict__ w2, float* __restrict__ bt) {
  int e = blockIdx.x;                       // 0..528
  float t0 = cpb_coord(e / 23);
  float t1 = cpb_coord(e % 23);
  float acc[12];
#pragma unroll
  for (int h = 0; h < 12; h++) acc[h] = 0.0f;
  for (int u = threadIdx.x; u < 512; u += 64) {
    float hv = fmaxf(fmaf(t0, w1[u], fmaf(t1, w1[512 + u], b1[u])), 0.0f);
#pragma unroll
    for (int h = 0; h < 12; h++) acc[h] = fmaf(hv, w2[u * 12 + h], acc[h]);
  }
#pragma unroll
  for (int h = 0; h < 12; h++)
    for (int m = 1; m < 64; m <<= 1) acc[h] += __shfl_xor(acc[h], m);
  if (threadIdx.x == 0) {
#pragma unroll
    for (int h = 0; h < 12; h++) bt[e * 12 + h] = acc[h];
  }
}

// plain layout [h][i][j] (f32): the swapped-QK attn reads a contiguous float4
// along j (j = tj*16 + g*4, 16B-aligned).
__global__ void k_cpb2(const float* __restrict__ bt, float* __restrict__ rb) {
  int h = blockIdx.x / 144, i = blockIdx.x % 144;
  int j = threadIdx.x;
  if (j >= 144) return;
  int yi = i / 12, xi = i % 12, yj = j / 12, xj = j % 12;
  int idx = (yi - yj + 11) * 23 + (xi - xj + 11);
  float v = bt[idx * 12 + h];
  rb[((size_t)h * 144 + i) * 144 + j] = 16.0f / (1.0f + expf(-v));
}

// ---------------- GEMM: C[M x N] = A[M x K] * Bt[N x K]^T ----------------
// 128x128 tile, BK=32, DOUBLE-BUFFERED (2x(As+Bs) = 32 KB, same footprint as
// the old single-buffered BK=64). Per step: stage tile t+1 into buf^1 (async
// global_load_lds), compute tile t from buf, one barrier. Load latency hides
// under the 16-MFMA compute phase.
// Swizzle (both-sides): physical 16B block p of row r holds logical block
// p ^ ((r>>1)&3); source pre-swizzled, fragment read applies same involution.
// Epilogues unchanged from R16 (C-tile reuses the 32 KB Smem).
template <int EPI>
__global__ __launch_bounds__(256) void k_gemm(
    const ushort* __restrict__ A, const ushort* __restrict__ Bt, int K, int NB,
    const float* __restrict__ bias0, const float* __restrict__ bias1,
    ushort* __restrict__ O0, ushort* __restrict__ O1, ushort* __restrict__ O2,
    float* __restrict__ FO) {
  __shared__ __align__(16) ushort Smem[2 * 2 * 128 * 32];  // buf0:{As,Bs} buf1:{As,Bs}
  const int tid = threadIdx.x;
  const int lane = tid & 63, w = tid >> 6;
  const int wr = w >> 1, wc = w & 1;
  const int l15 = lane & 15, g = lane >> 4;

  const int per = gridDim.x >> 3;
  const int bid = (blockIdx.x & 7) * per + (blockIdx.x >> 3);
  const int bm = bid / NB, bn = bid % NB;

  f32x4 acc[4][4];
#pragma unroll
  for (int m = 0; m < 4; m++)
#pragma unroll
    for (int n = 0; n < 4; n++) acc[m][n] = (f32x4){0.f, 0.f, 0.f, 0.f};

  const size_t arow0 = (size_t)bm * 128;
  const size_t brow0 = (size_t)bn * 128;

  // staging: chunk = 16 rows x 32 cols (1 KB); 8 chunks per matrix per step;
  // wave w stages chunks {2w, 2w+1}. lane l: srow = l>>2 (row in chunk),
  // physical block l&3 sources logical block (l&3) ^ ((srow>>1)&3).
  const int srow = lane >> 2;
  const int sblk = (lane & 3) ^ ((srow >> 1) & 3);
  const size_t soff = (size_t)srow * K + sblk * 8;

#define GEMM_STAGE(BUF, K0)                                                      \
  do {                                                                           \
    ushort* As_ = &Smem[(BUF) * 8192];                                           \
    ushort* Bs_ = &Smem[(BUF) * 8192 + 4096];                                    \
    _Pragma("unroll")                                                            \
    for (int i_ = 0; i_ < 2; i_++) {                                             \
      int c_ = w * 2 + i_;                                                       \
      gload_lds16(&A[(arow0 + c_ * 16) * (size_t)K + (K0) + soff], &As_[c_ * 512]); \
      gload_lds16(&Bt[(brow0 + c_ * 16) * (size_t)K + (K0) + soff], &Bs_[c_ * 512]);\
    }                                                                            \
  } while (0)

  GEMM_STAGE(0, 0);
  __syncthreads();

  int cur = 0;
  for (int k0 = 0; k0 < K; k0 += 32) {
    if (k0 + 32 < K) GEMM_STAGE(cur ^ 1, k0 + 32);
    const ushort* As = &Smem[cur * 8192];
    const ushort* Bs = &Smem[cur * 8192 + 4096];
    short8 af[4], bf[4];
#pragma unroll
    for (int m = 0; m < 4; m++) {
      int row = wr * 64 + m * 16 + l15;
      af[m] = *(const short8*)&As[row * 32 + ((g ^ ((row >> 1) & 3)) << 3)];
    }
#pragma unroll
    for (int n = 0; n < 4; n++) {
      int row = wc * 64 + n * 16 + l15;
      bf[n] = *(const short8*)&Bs[row * 32 + ((g ^ ((row >> 1) & 3)) << 3)];
    }
#pragma unroll
    for (int m = 0; m < 4; m++)
#pragma unroll
      for (int n = 0; n < 4; n++) acc[m][n] = mfma16(af[m], bf[n], acc[m][n]);
    __syncthreads();
    cur ^= 1;
  }
#undef GEMM_STAGE

  unsigned char* Cb = (unsigned char*)Smem;

  if (EPI == 0) {
    const int sec = bn / 3;                        // 0=Q 1=K 2=V
    const int cbase = (bn - sec * 3) * 128;
    if (sec == 2) {
      float vb4[4];
#pragma unroll
      for (int n = 0; n < 4; n++) vb4[n] = bias1[cbase + wc * 64 + n * 16 + l15];
#pragma unroll
      for (int m = 0; m < 4; m++) {
        int rbase = bm * 128 + wr * 64 + m * 16 + g * 4;
        int b = rbase / 144, nn = rbase - b * 144;
#pragma unroll
        for (int n = 0; n < 4; n++) {
          int cc = cbase + wc * 64 + n * 16 + l15;
          int head = cc >> 5, d = cc & 31;
          ushort4 pk;
          pk.x = f2b(acc[m][n][0] + vb4[n]);
          pk.y = f2b(acc[m][n][1] + vb4[n]);
          pk.z = f2b(acc[m][n][2] + vb4[n]);
          pk.w = f2b(acc[m][n][3] + vb4[n]);
          *(ushort4*)&O2[(((size_t)b * 12 + head) * 32 + d) * 144 + nn] = pk;
        }
      }
    } else {
      float bn4[4];
#pragma unroll
      for (int n = 0; n < 4; n++)
        bn4[n] = (sec == 0) ? bias0[cbase + wc * 64 + n * 16 + l15] : 0.0f;
#pragma unroll
      for (int m = 0; m < 4; m++)
#pragma unroll
        for (int n = 0; n < 4; n++) {
          int col = wc * 64 + n * 16 + l15;
#pragma unroll
          for (int e = 0; e < 4; e++) {
            int row = wr * 64 + m * 16 + g * 4 + e;
            int sblk2 = (col >> 3) ^ ((row >> 2) & 7);
            *(ushort*)&Cb[row * 256 + sblk2 * 16 + (col & 7) * 2] =
                f2b(acc[m][n][e] + bn4[n]);
          }
        }
      __syncthreads();
      int r = tid >> 1, half = tid & 1;
      int grow = bm * 128 + r;
      int b = grow / 144, nn = grow - b * 144;
      ushort* dst = (sec == 0) ? O0 : O1;
#pragma unroll
      for (int j = 0; j < 8; j++) {
        int lb = half * 8 + j;
        int sblk2 = lb ^ ((r >> 2) & 7);
        uint4 v = *(uint4*)&Cb[r * 256 + sblk2 * 16];
        int c0 = cbase + lb * 8;
        int head = c0 >> 5, d0 = c0 & 31;
        *(uint4*)&dst[(((size_t)b * 12 + head) * 144 + nn) * 32 + d0] = v;
      }
    }
  } else {
    float bn4[4];
#pragma unroll
    for (int n = 0; n < 4; n++) bn4[n] = bias0[bn * 128 + wc * 64 + n * 16 + l15];
#pragma unroll
    for (int p = 0; p < 2; p++) {
      if (wc == p) {
#pragma unroll
        for (int m = 0; m < 4; m++)
#pragma unroll
          for (int n = 0; n < 4; n++) {
            int lcol = n * 16 + l15;
#pragma unroll
            for (int e = 0; e < 4; e++) {
              int row = wr * 64 + m * 16 + g * 4 + e;
              int sblk2 = (lcol >> 2) ^ ((row >> 2) & 7);
              *(float*)&Cb[row * 256 + sblk2 * 16 + (lcol & 3) * 4] =
                  acc[m][n][e] + bn4[n];
            }
          }
      }
      __syncthreads();
      int r = tid >> 1, half = tid & 1;
#pragma unroll
      for (int j = 0; j < 8; j++) {
        int lb = half * 8 + j;
        int sblk2 = lb ^ ((r >> 2) & 7);
        uint4 v = *(uint4*)&Cb[r * 256 + sblk2 * 16];
        *(uint4*)&FO[(size_t)(bm * 128 + r) * 384 + bn * 128 + p * 64 + lb * 4] = v;
      }
      __syncthreads();
    }
  }
}

// ---------------- fused window attention (EXACT R16 source) ------------------
// one block per (b,h); 4 waves; wave w owns row-tiles ti = w, w+4, w+8.
// Swapped-operand QK^T: lane (l15,g) holds S[q=ti*16+l15][k=tj*16+g*4+e];
// lane-local softmax (2 shfl, 1 divide), packed 8B P-writes, constant shift.
__global__ __launch_bounds__(256, 3) void k_attn(
    const ushort* __restrict__ Qg, const ushort* __restrict__ Kg, const ushort* __restrict__ VTg,
    const float* __restrict__ lsc, const float* __restrict__ relb, ushort* __restrict__ AO) {
  __shared__ ushort Qs[144 * 32];
  __shared__ ushort Ks[144 * 32];
  __shared__ ushort Vt[32 * 168];
  __shared__ ushort Pw[4][16 * 168];
  __shared__ float rq[144], rk[144];

  const int tid = threadIdx.x;
  const int lane = tid & 63, w = tid >> 6;
  const int l15 = lane & 15, g = lane >> 4;
  const int bh = blockIdx.x;
  const int b = bh / 12, h = bh % 12;
  const size_t base = (size_t)bh * 4608;

  // stage Q,K (swizzled 16B blocks) + fused row norms (4-thread groups)
  for (int f = tid; f < 576; f += 256) {
    int row = f >> 2, oct = f & 3;
    union { uint4 v; ushort u[8]; } qv, kv;
    qv.v = *(const uint4*)&Qg[base + row * 32 + oct * 8];
    kv.v = *(const uint4*)&Kg[base + row * 32 + oct * 8];
    int blk = (oct ^ (row & 3)) << 3;
    *(uint4*)&Qs[row * 32 + blk] = qv.v;
    *(uint4*)&Ks[row * 32 + blk] = kv.v;
    float sq = 0.f, sk = 0.f;
#pragma unroll
    for (int j = 0; j < 8; j++) {
      float xq = b2f(qv.u[j]); sq = fmaf(xq, xq, sq);
      float xk = b2f(kv.u[j]); sk = fmaf(xk, xk, sk);
    }
    sq += __shfl_xor(sq, 1); sq += __shfl_xor(sq, 2);
    sk += __shfl_xor(sk, 1); sk += __shfl_xor(sk, 2);
    if (oct == 0) {
      rq[row] = rsqrtf(fmaxf(sq, 1e-12f));
      rk[row] = rsqrtf(fmaxf(sk, 1e-12f));
    }
  }
  // stage V^T rows (coalesced)
  for (int f = tid; f < 576; f += 256) {
    int d = f / 18, j = f % 18;
    *(uint4*)&Vt[d * 168 + j * 8] = *(const uint4*)&VTg[base + d * 144 + j * 8];
  }
  // zero-pad Vt cols [144,160)
  if (tid < 64) {
    int d = tid >> 1, j = tid & 1;
    *(uint4*)&Vt[d * 168 + 144 + j * 8] = (uint4){0, 0, 0, 0};
  }
  // zero-pad this wave's P cols [144,160)
  if (lane < 32) {
    int r = lane >> 1, j = lane & 1;
    *(uint4*)&Pw[w][r * 168 + 144 + j * 8] = (uint4){0, 0, 0, 0};
  }
  __syncthreads();

  // hoist K fragments + rk (as contiguous float4 per k-tile) to registers
  short8 kf[9];
  f32x4 rk4[9];
#pragma unroll
  for (int tj = 0; tj < 9; tj++) {
    int R = tj * 16 + l15;
    kf[tj] = *(const short8*)&Ks[R * 32 + ((g ^ (R & 3)) << 3)];
    rk4[tj] = *(const f32x4*)&rk[tj * 16 + g * 4];
  }

  const float sc = __expf(fminf(lsc[h], 4.6051702f));   // exp(min(ls, log 100))
  const float shift = sc + 16.0f;                       // >= max possible logit
  const float* rbh = relb + (size_t)h * (144 * 144);

  for (int ti = w; ti < 9; ti += 4) {
    int RQ = ti * 16 + l15;
    short8 aq = *(const short8*)&Qs[RQ * 32 + ((g ^ (RQ & 3)) << 3)];
    // swapped: s[tj][e] = S[q = ti*16+l15][k = tj*16+g*4+e]
    f32x4 s[9];
#pragma unroll
    for (int tj = 0; tj < 9; tj++) {
      f32x4 z = {0.f, 0.f, 0.f, 0.f};
      s[tj] = mfma16(kf[tj], aq, z);
    }
    const float rq_l = rq[RQ] * sc;                     // this lane's q-row scale
    const float* rbq = rbh + (size_t)RQ * 144;

    // logits -> exp(shifted) -> lane-local row sum
    float lg[9][4];
    float ssum = 0.f;
#pragma unroll
    for (int tj = 0; tj < 9; tj++) {
      f32x4 rbv = *(const f32x4*)&rbq[tj * 16 + g * 4];
#pragma unroll
      for (int e = 0; e < 4; e++) {
        float v = fmaf(s[tj][e] * rq_l, rk4[tj][e], rbv[e]);
        v = __expf(v - shift);
        lg[tj][e] = v;
        ssum += v;
      }
    }
    ssum += __shfl_xor(ssum, 16);
    ssum += __shfl_xor(ssum, 32);
    const float inv = 1.0f / ssum;

    // write P (bf16): lane's 4 contiguous k-cols per tj -> one 8B store
#pragma unroll
    for (int tj = 0; tj < 9; tj++) {
      ushort4 pk;
      pk.x = f2b(lg[tj][0] * inv);
      pk.y = f2b(lg[tj][1] * inv);
      pk.z = f2b(lg[tj][2] * inv);
      pk.w = f2b(lg[tj][3] * inv);
      *(ushort4*)&Pw[w][l15 * 168 + tj * 16 + g * 4] = pk;
    }

    asm volatile("s_waitcnt lgkmcnt(0)" ::: "memory");
    __builtin_amdgcn_sched_barrier(0);

    // PV: out[16 x 32] = P[16 x 160] * V[160 x 32] (zero-padded K)
#pragma unroll
    for (int dt = 0; dt < 2; dt++) {
      f32x4 o = {0.f, 0.f, 0.f, 0.f};
#pragma unroll
      for (int ks = 0; ks < 5; ks++) {
        short8 ap = *(const short8*)&Pw[w][l15 * 168 + ks * 32 + g * 8];
        short8 bv = *(const short8*)&Vt[(dt * 16 + l15) * 168 + ks * 32 + g * 8];
        o = mfma16(ap, bv, o);
      }
      ushort* dst = &AO[((size_t)b * 144 + ti * 16 + g * 4) * 384 + h * 32 + dt * 16 + l15];
#pragma unroll
      for (int e = 0; e < 4; e++) dst[(size_t)e * 384] = f2b(o[e]);
    }
  }
}

// ---------------- launch ----------------
extern "C" void kernel_launch(void* const* d_in, const int* in_sizes, int n_in,
                              void* d_out, int out_size, void* d_ws, size_t ws_size,
                              hipStream_t stream) {
  const float* x     = (const float*)d_in[0];
  const float* wqkv  = (const float*)d_in[1];
  const float* qbias = (const float*)d_in[2];
  const float* vbias = (const float*)d_in[3];
  const float* lsc   = (const float*)d_in[4];
  const float* cw1   = (const float*)d_in[5];
  const float* cb1   = (const float*)d_in[6];
  const float* cw2   = (const float*)d_in[7];
  const float* pw    = (const float*)d_in[8];
  const float* pb    = (const float*)d_in[9];

  char* ws = (char*)d_ws;
  ushort* xb = (ushort*)(ws);                  // 56,623,104 B  (x bf16; later aliased as attn_out)
  ushort* wt = (ushort*)(ws + 56623104);       //    884,736 B  (W_qkv^T bf16 [1152][384])
  ushort* pt = (ushort*)(ws + 57507840);       //    294,912 B  (proj_w^T bf16 [384][384])
  ushort* qb = (ushort*)(ws + 57802752);       // 56,623,104 B  (Q bf16 [B,H,144,32])
  ushort* kb = (ushort*)(ws + 114425856);      // 56,623,104 B  (K bf16 [B,H,144,32])
  ushort* vb = (ushort*)(ws + 171048960);      // 56,623,104 B  (V^T bf16 [B,H,32,144])
  float*  bt = (float*)(ws + 227672064);       //     25,392 B  (bias_table [529][12])
  float*  rb = (float*)(ws + 227697456);       //    995,328 B  (rel_bias [12][144][144])
  ushort* ao = xb;                             // alias: x_bf16 dead after qkv GEMM

  k_cvtx<<<13824, 256, 0, stream>>>(x, xb);
  k_cvtT<<<384, 256, 0, stream>>>(wqkv, wt, 384, 1152);
  k_cvtT<<<384, 256, 0, stream>>>(pw, pt, 384, 384);
  k_cpb1<<<529, 64, 0, stream>>>(cw1, cb1, cw2, bt);
  k_cpb2<<<1728, 144, 0, stream>>>(bt, rb);
  k_gemm<0><<<5184, 256, 0, stream>>>(xb, wt, 384, 9, qbias, vbias, qb, kb, vb, nullptr);
  k_attn<<<6144, 256, 0, stream>>>(qb, kb, vb, lsc, rb, ao);
  k_gemm<1><<<1728, 256, 0, stream>>>(ao, pt, 384, 3, pb, nullptr, nullptr, nullptr, nullptr, (float*)d_out);
}

// Round 18
// 283.986 us; speedup vs baseline: 1.0297x; 1.0297x over previous
//
#include <hip/hip_runtime.h>
#include <hip/hip_bf16.h>
#include <cstdint>
#include <cstddef>

typedef __attribute__((ext_vector_type(8))) short short8;
typedef __attribute__((ext_vector_type(4))) float f32x4;

__device__ __forceinline__ float b2f(ushort u) {
  union { float f; uint32_t i; } x; x.i = ((uint32_t)u) << 16; return x.f;
}
__device__ __forceinline__ ushort f2b(float f) {
  uint32_t i = __builtin_bit_cast(uint32_t, f);
  i += 0x7fffu + ((i >> 16) & 1u);   // RNE
  return (ushort)(i >> 16);
}
__device__ __forceinline__ f32x4 mfma16(short8 a, short8 b, f32x4 c) {
  asm("v_mfma_f32_16x16x32_bf16 %0, %1, %2, %0" : "+v"(c) : "v"(a), "v"(b));
  return c;
}
__device__ __forceinline__ void gload_lds16(const void* g, void* l) {
  auto gp = reinterpret_cast<const __attribute__((address_space(1))) uint32_t*>(
      reinterpret_cast<uintptr_t>(g));
  auto lp = reinterpret_cast<__attribute__((address_space(3))) uint32_t*>(
      reinterpret_cast<uintptr_t>(l));
  __builtin_amdgcn_global_load_lds(gp, lp, 16, 0, 0);
}

// ---------------- conversion kernels ----------------
__global__ __launch_bounds__(256) void k_cvtx(const float* __restrict__ x, ushort* __restrict__ o) {
  size_t i = (size_t)blockIdx.x * 256 + threadIdx.x;           // one per 8 elems
  const float4* xp = (const float4*)x;
  float4 a = xp[i * 2], b = xp[i * 2 + 1];
  union { short8 v; ushort u[8]; } r;
  r.u[0] = f2b(a.x); r.u[1] = f2b(a.y); r.u[2] = f2b(a.z); r.u[3] = f2b(a.w);
  r.u[4] = f2b(b.x); r.u[5] = f2b(b.y); r.u[6] = f2b(b.z); r.u[7] = f2b(b.w);
  *(short8*)&o[i * 8] = r.v;
}

// W[R][C] -> Wt[C][R] (bf16)
__global__ __launch_bounds__(256) void k_cvtT(const float* __restrict__ W, ushort* __restrict__ Wt,
                                              int R, int C) {
  int r = blockIdx.x;
  for (int c = threadIdx.x; c < C; c += 256)
    Wt[(size_t)c * R + r] = f2b(W[(size_t)r * C + c]);
}

// ---------------- CPB (continuous position bias) ----------------
__device__ __forceinline__ float cpb_coord(int i) {
  float v = (float)(i - 11) * (8.0f / 11.0f);
  float l = log2f(fabsf(v) + 1.0f) * (1.0f / 3.0f);
  return v < 0.0f ? -l : l;
}

__global__ void k_cpb1(const float* __restrict__ w1, const float* __restrict__ b1,
                       const float* __restrict__ w2, float* __restrict__ bt) {
  int e = blockIdx.x;                       // 0..528
  float t0 = cpb_coord(e / 23);
  float t1 = cpb_coord(e % 23);
  float acc[12];
#pragma unroll
  for (int h = 0; h < 12; h++) acc[h] = 0.0f;
  for (int u = threadIdx.x; u < 512; u += 64) {
    float hv = fmaxf(fmaf(t0, w1[u], fmaf(t1, w1[512 + u], b1[u])), 0.0f);
#pragma unroll
    for (int h = 0; h < 12; h++) acc[h] = fmaf(hv, w2[u * 12 + h], acc[h]);
  }
#pragma unroll
  for (int h = 0; h < 12; h++)
    for (int m = 1; m < 64; m <<= 1) acc[h] += __shfl_xor(acc[h], m);
  if (threadIdx.x == 0) {
#pragma unroll
    for (int h = 0; h < 12; h++) bt[e * 12 + h] = acc[h];
  }
}

// plain layout [h][i][j] (f32): the swapped-QK attn reads a contiguous float4
// along j (j = tj*16 + g*4, 16B-aligned).
__global__ void k_cpb2(const float* __restrict__ bt, float* __restrict__ rb) {
  int h = blockIdx.x / 144, i = blockIdx.x % 144;
  int j = threadIdx.x;
  if (j >= 144) return;
  int yi = i / 12, xi = i % 12, yj = j / 12, xj = j % 12;
  int idx = (yi - yj + 11) * 23 + (xi - xj + 11);
  float v = bt[idx * 12 + h];
  rb[((size_t)h * 144 + i) * 144 + j] = 16.0f / (1.0f + expf(-v));
}

// ---------------- GEMM: C[M x N] = A[M x K] * Bt[N x K]^T ----------------
// 128x128 tile, BK=64, single-buffered (the proven 2-barrier structure).
// global_load_lds width-16 staging, source pre-swizzled (slot s of row r holds
// block s ^ (r&7)), ds_read applies the same involution.
// Epilogue through the (dead) staging LDS for coalesced stores.
// EPI 0: qkv -> Q,K bf16 [B,H,144,32]; V stored TRANSPOSED [B,H,32,144]
// EPI 1: proj -> f32 out + proj_b
template <int EPI>
__global__ __launch_bounds__(256) void k_gemm(
    const ushort* __restrict__ A, const ushort* __restrict__ Bt, int K, int NB,
    const float* __restrict__ bias0, const float* __restrict__ bias1,
    ushort* __restrict__ O0, ushort* __restrict__ O1, ushort* __restrict__ O2,
    float* __restrict__ FO) {
  __shared__ __align__(16) ushort Smem[2 * 128 * 64];   // As | Bs, reused as C-tile
  ushort* As = Smem;
  ushort* Bs = Smem + 128 * 64;
  const int tid = threadIdx.x;
  const int lane = tid & 63, w = tid >> 6;
  const int wr = w >> 1, wc = w & 1;
  const int l15 = lane & 15, g = lane >> 4;

  const int per = gridDim.x >> 3;
  const int bid = (blockIdx.x & 7) * per + (blockIdx.x >> 3);
  const int bm = bid / NB, bn = bid % NB;

  f32x4 acc[4][4];
#pragma unroll
  for (int m = 0; m < 4; m++)
#pragma unroll
    for (int n = 0; n < 4; n++) acc[m][n] = (f32x4){0.f, 0.f, 0.f, 0.f};

  const size_t arow0 = (size_t)bm * 128;
  const size_t brow0 = (size_t)bn * 128;

  const int srow = lane >> 3;
  const int sblk0 = (lane & 7) ^ srow;
  const size_t soff = (size_t)srow * K + sblk0 * 8;

  for (int k0 = 0; k0 < K; k0 += 64) {
#pragma unroll
    for (int i = 0; i < 4; i++) {
      int c = i * 4 + w;
      gload_lds16(&A[(arow0 + c * 8) * (size_t)K + k0 + soff], &As[c * 512]);
      gload_lds16(&Bt[(brow0 + c * 8) * (size_t)K + k0 + soff], &Bs[c * 512]);
    }
    __syncthreads();
#pragma unroll
    for (int ks = 0; ks < 2; ks++) {
      short8 af[4], bf[4];
#pragma unroll
      for (int m = 0; m < 4; m++) {
        int row = wr * 64 + m * 16 + l15;
        af[m] = *(const short8*)&As[row * 64 + (((ks * 4 + g) ^ (row & 7)) << 3)];
      }
#pragma unroll
      for (int n = 0; n < 4; n++) {
        int row = wc * 64 + n * 16 + l15;
        bf[n] = *(const short8*)&Bs[row * 64 + (((ks * 4 + g) ^ (row & 7)) << 3)];
      }
#pragma unroll
      for (int m = 0; m < 4; m++)
#pragma unroll
        for (int n = 0; n < 4; n++) acc[m][n] = mfma16(af[m], bf[n], acc[m][n]);
    }
    __syncthreads();
  }

  unsigned char* Cb = (unsigned char*)Smem;

  if (EPI == 0) {
    const int sec = bn / 3;                        // 0=Q 1=K 2=V
    const int cbase = (bn - sec * 3) * 128;
    if (sec == 2) {
      float vb4[4];
#pragma unroll
      for (int n = 0; n < 4; n++) vb4[n] = bias1[cbase + wc * 64 + n * 16 + l15];
#pragma unroll
      for (int m = 0; m < 4; m++) {
        int rbase = bm * 128 + wr * 64 + m * 16 + g * 4;
        int b = rbase / 144, nn = rbase - b * 144;
#pragma unroll
        for (int n = 0; n < 4; n++) {
          int cc = cbase + wc * 64 + n * 16 + l15;
          int head = cc >> 5, d = cc & 31;
          ushort4 pk;
          pk.x = f2b(acc[m][n][0] + vb4[n]);
          pk.y = f2b(acc[m][n][1] + vb4[n]);
          pk.z = f2b(acc[m][n][2] + vb4[n]);
          pk.w = f2b(acc[m][n][3] + vb4[n]);
          *(ushort4*)&O2[(((size_t)b * 12 + head) * 32 + d) * 144 + nn] = pk;
        }
      }
    } else {
      float bn4[4];
#pragma unroll
      for (int n = 0; n < 4; n++)
        bn4[n] = (sec == 0) ? bias0[cbase + wc * 64 + n * 16 + l15] : 0.0f;
#pragma unroll
      for (int m = 0; m < 4; m++)
#pragma unroll
        for (int n = 0; n < 4; n++) {
          int col = wc * 64 + n * 16 + l15;
#pragma unroll
          for (int e = 0; e < 4; e++) {
            int row = wr * 64 + m * 16 + g * 4 + e;
            int sblk = (col >> 3) ^ ((row >> 2) & 7);
            *(ushort*)&Cb[row * 256 + sblk * 16 + (col & 7) * 2] =
                f2b(acc[m][n][e] + bn4[n]);
          }
        }
      __syncthreads();
      int r = tid >> 1, half = tid & 1;
      int grow = bm * 128 + r;
      int b = grow / 144, nn = grow - b * 144;
      ushort* dst = (sec == 0) ? O0 : O1;
#pragma unroll
      for (int j = 0; j < 8; j++) {
        int lb = half * 8 + j;
        int sblk = lb ^ ((r >> 2) & 7);
        uint4 v = *(uint4*)&Cb[r * 256 + sblk * 16];
        int c0 = cbase + lb * 8;
        int head = c0 >> 5, d0 = c0 & 31;
        *(uint4*)&dst[(((size_t)b * 12 + head) * 144 + nn) * 32 + d0] = v;
      }
    }
  } else {
    float bn4[4];
#pragma unroll
    for (int n = 0; n < 4; n++) bn4[n] = bias0[bn * 128 + wc * 64 + n * 16 + l15];
#pragma unroll
    for (int p = 0; p < 2; p++) {
      if (wc == p) {
#pragma unroll
        for (int m = 0; m < 4; m++)
#pragma unroll
          for (int n = 0; n < 4; n++) {
            int lcol = n * 16 + l15;
#pragma unroll
            for (int e = 0; e < 4; e++) {
              int row = wr * 64 + m * 16 + g * 4 + e;
              int sblk = (lcol >> 2) ^ ((row >> 2) & 7);
              *(float*)&Cb[row * 256 + sblk * 16 + (lcol & 3) * 4] =
                  acc[m][n][e] + bn4[n];
            }
          }
      }
      __syncthreads();
      int r = tid >> 1, half = tid & 1;
#pragma unroll
      for (int j = 0; j < 8; j++) {
        int lb = half * 8 + j;
        int sblk = lb ^ ((r >> 2) & 7);
        uint4 v = *(uint4*)&Cb[r * 256 + sblk * 16];
        *(uint4*)&FO[(size_t)(bm * 128 + r) * 384 + bn * 128 + p * 64 + lb * 4] = v;
      }
      __syncthreads();
    }
  }
}

// ---------------- fused window attention (swapped-operand QK^T) --------------
// one block per (b,h); 4 waves; wave w owns row-tiles ti = w, w+4, w+8.
// Swapped QK^T: lane (l15,g) holds S[q=ti*16+l15][k=tj*16+g*4+e]; lane-local
// softmax (2 shfl, 1 divide), packed 8B P-writes, constant-shift exp.
__global__ __launch_bounds__(256, 3) void k_attn(
    const ushort* __restrict__ Qg, const ushort* __restrict__ Kg, const ushort* __restrict__ VTg,
    const float* __restrict__ lsc, const float* __restrict__ relb, ushort* __restrict__ AO) {
  __shared__ ushort Qs[144 * 32];
  __shared__ ushort Ks[144 * 32];
  __shared__ ushort Vt[32 * 168];
  __shared__ ushort Pw[4][16 * 168];
  __shared__ float rq[144], rk[144];

  const int tid = threadIdx.x;
  const int lane = tid & 63, w = tid >> 6;
  const int l15 = lane & 15, g = lane >> 4;
  const int bh = blockIdx.x;
  const int b = bh / 12, h = bh % 12;
  const size_t base = (size_t)bh * 4608;

  // stage Q,K (swizzled 16B blocks) + fused row norms (4-thread groups)
  for (int f = tid; f < 576; f += 256) {
    int row = f >> 2, oct = f & 3;
    union { uint4 v; ushort u[8]; } qv, kv;
    qv.v = *(const uint4*)&Qg[base + row * 32 + oct * 8];
    kv.v = *(const uint4*)&Kg[base + row * 32 + oct * 8];
    int blk = (oct ^ (row & 3)) << 3;
    *(uint4*)&Qs[row * 32 + blk] = qv.v;
    *(uint4*)&Ks[row * 32 + blk] = kv.v;
    float sq = 0.f, sk = 0.f;
#pragma unroll
    for (int j = 0; j < 8; j++) {
      float xq = b2f(qv.u[j]); sq = fmaf(xq, xq, sq);
      float xk = b2f(kv.u[j]); sk = fmaf(xk, xk, sk);
    }
    sq += __shfl_xor(sq, 1); sq += __shfl_xor(sq, 2);
    sk += __shfl_xor(sk, 1); sk += __shfl_xor(sk, 2);
    if (oct == 0) {
      rq[row] = rsqrtf(fmaxf(sq, 1e-12f));
      rk[row] = rsqrtf(fmaxf(sk, 1e-12f));
    }
  }
  // stage V^T rows (coalesced)
  for (int f = tid; f < 576; f += 256) {
    int d = f / 18, j = f % 18;
    *(uint4*)&Vt[d * 168 + j * 8] = *(const uint4*)&VTg[base + d * 144 + j * 8];
  }
  // zero-pad Vt cols [144,160)
  if (tid < 64) {
    int d = tid >> 1, j = tid & 1;
    *(uint4*)&Vt[d * 168 + 144 + j * 8] = (uint4){0, 0, 0, 0};
  }
  // zero-pad this wave's P cols [144,160)
  if (lane < 32) {
    int r = lane >> 1, j = lane & 1;
    *(uint4*)&Pw[w][r * 168 + 144 + j * 8] = (uint4){0, 0, 0, 0};
  }
  __syncthreads();

  // hoist K fragments + rk (as contiguous float4 per k-tile) to registers
  short8 kf[9];
  f32x4 rk4[9];
#pragma unroll
  for (int tj = 0; tj < 9; tj++) {
    int R = tj * 16 + l15;
    kf[tj] = *(const short8*)&Ks[R * 32 + ((g ^ (R & 3)) << 3)];
    rk4[tj] = *(const f32x4*)&rk[tj * 16 + g * 4];
  }

  const float sc = __expf(fminf(lsc[h], 4.6051702f));   // exp(min(ls, log 100))
  const float shift = sc + 16.0f;                       // >= max possible logit
  const float* rbh = relb + (size_t)h * (144 * 144);

  for (int ti = w; ti < 9; ti += 4) {
    int RQ = ti * 16 + l15;
    short8 aq = *(const short8*)&Qs[RQ * 32 + ((g ^ (RQ & 3)) << 3)];
    // swapped: s[tj][e] = S[q = ti*16+l15][k = tj*16+g*4+e]
    f32x4 s[9];
#pragma unroll
    for (int tj = 0; tj < 9; tj++) {
      f32x4 z = {0.f, 0.f, 0.f, 0.f};
      s[tj] = mfma16(kf[tj], aq, z);
    }
    const float rq_l = rq[RQ] * sc;                     // this lane's q-row scale
    const float* rbq = rbh + (size_t)RQ * 144;

    // logits -> exp(shifted) -> lane-local row sum
    float lg[9][4];
    float ssum = 0.f;
#pragma unroll
    for (int tj = 0; tj < 9; tj++) {
      f32x4 rbv = *(const f32x4*)&rbq[tj * 16 + g * 4];
#pragma unroll
      for (int e = 0; e < 4; e++) {
        float v = fmaf(s[tj][e] * rq_l, rk4[tj][e], rbv[e]);
        v = __expf(v - shift);
        lg[tj][e] = v;
        ssum += v;
      }
    }
    ssum += __shfl_xor(ssum, 16);
    ssum += __shfl_xor(ssum, 32);
    const float inv = 1.0f / ssum;

    // write P (bf16): lane's 4 contiguous k-cols per tj -> one 8B store
#pragma unroll
    for (int tj = 0; tj < 9; tj++) {
      ushort4 pk;
      pk.x = f2b(lg[tj][0] * inv);
      pk.y = f2b(lg[tj][1] * inv);
      pk.z = f2b(lg[tj][2] * inv);
      pk.w = f2b(lg[tj][3] * inv);
      *(ushort4*)&Pw[w][l15 * 168 + tj * 16 + g * 4] = pk;
    }

    asm volatile("s_waitcnt lgkmcnt(0)" ::: "memory");
    __builtin_amdgcn_sched_barrier(0);

    // PV: out[16 x 32] = P[16 x 160] * V[160 x 32] (zero-padded K)
#pragma unroll
    for (int dt = 0; dt < 2; dt++) {
      f32x4 o = {0.f, 0.f, 0.f, 0.f};
#pragma unroll
      for (int ks = 0; ks < 5; ks++) {
        short8 ap = *(const short8*)&Pw[w][l15 * 168 + ks * 32 + g * 8];
        short8 bv = *(const short8*)&Vt[(dt * 16 + l15) * 168 + ks * 32 + g * 8];
        o = mfma16(ap, bv, o);
      }
      ushort* dst = &AO[((size_t)b * 144 + ti * 16 + g * 4) * 384 + h * 32 + dt * 16 + l15];
#pragma unroll
      for (int e = 0; e < 4; e++) dst[(size_t)e * 384] = f2b(o[e]);
    }
  }
}

// ---------------- launch ----------------
extern "C" void kernel_launch(void* const* d_in, const int* in_sizes, int n_in,
                              void* d_out, int out_size, void* d_ws, size_t ws_size,
                              hipStream_t stream) {
  const float* x     = (const float*)d_in[0];
  const float* wqkv  = (const float*)d_in[1];
  const float* qbias = (const float*)d_in[2];
  const float* vbias = (const float*)d_in[3];
  const float* lsc   = (const float*)d_in[4];
  const float* cw1   = (const float*)d_in[5];
  const float* cb1   = (const float*)d_in[6];
  const float* cw2   = (const float*)d_in[7];
  const float* pw    = (const float*)d_in[8];
  const float* pb    = (const float*)d_in[9];

  char* ws = (char*)d_ws;
  ushort* xb = (ushort*)(ws);                  // 56,623,104 B  (x bf16; later aliased as attn_out)
  ushort* wt = (ushort*)(ws + 56623104);       //    884,736 B  (W_qkv^T bf16 [1152][384])
  ushort* pt = (ushort*)(ws + 57507840);       //    294,912 B  (proj_w^T bf16 [384][384])
  ushort* qb = (ushort*)(ws + 57802752);       // 56,623,104 B  (Q bf16 [B,H,144,32])
  ushort* kb = (ushort*)(ws + 114425856);      // 56,623,104 B  (K bf16 [B,H,144,32])
  ushort* vb = (ushort*)(ws + 171048960);      // 56,623,104 B  (V^T bf16 [B,H,32,144])
  float*  bt = (float*)(ws + 227672064);       //     25,392 B  (bias_table [529][12])
  float*  rb = (float*)(ws + 227697456);       //    995,328 B  (rel_bias [12][144][144])
  ushort* ao = xb;                             // alias: x_bf16 dead after qkv GEMM

  k_cvtx<<<13824, 256, 0, stream>>>(x, xb);
  k_cvtT<<<384, 256, 0, stream>>>(wqkv, wt, 384, 1152);
  k_cvtT<<<384, 256, 0, stream>>>(pw, pt, 384, 384);
  k_cpb1<<<529, 64, 0, stream>>>(cw1, cb1, cw2, bt);
  k_cpb2<<<1728, 144, 0, stream>>>(bt, rb);
  k_gemm<0><<<5184, 256, 0, stream>>>(xb, wt, 384, 9, qbias, vbias, qb, kb, vb, nullptr);
  k_attn<<<6144, 256, 0, stream>>>(qb, kb, vb, lsc, rb, ao);
  k_gemm<1><<<1728, 256, 0, stream>>>(ao, pt, 384, 3, pb, nullptr, nullptr, nullptr, nullptr, (float*)d_out);
}